// Round 1
// baseline (2976.142 us; speedup 1.0000x reference)
//
#include <hip/hip_runtime.h>

// ---------- types & helpers ----------
typedef __attribute__((ext_vector_type(8))) short bf16x8;
typedef __attribute__((ext_vector_type(8))) unsigned short ushort8;
typedef __attribute__((ext_vector_type(4))) float f32x4;

__device__ __forceinline__ unsigned short f2bf(float f) {
  union { float f; unsigned u; } v; v.f = f;
  unsigned r = (v.u + 0x7FFFu + ((v.u >> 16) & 1u)) >> 16;
  return (unsigned short)r;
}
__device__ __forceinline__ float bf2f(unsigned short h) {
  union { unsigned u; float f; } v; v.u = ((unsigned)h) << 16;
  return v.f;
}
__device__ __forceinline__ float sigm(float x) { return 1.f / (1.f + __expf(-x)); }
__device__ __forceinline__ float tanh_(float x) { return 1.f - 2.f / (__expf(2.f * x) + 1.f); }

#define GLDS(g, l) __builtin_amdgcn_global_load_lds( \
    (const __attribute__((address_space(1))) unsigned int*)(g), \
    (__attribute__((address_space(3))) unsigned int*)(l), 16, 0, 0)

// ---------- fp32 -> bf16 conversion (vectorized) ----------
__global__ void conv_bf16(const float* __restrict__ src, unsigned short* __restrict__ dst, int n4) {
  int i = blockIdx.x * blockDim.x + threadIdx.x;
  if (i >= n4) return;
  const float4 v = ((const float4*)src)[i];
  ushort4 o; o.x = f2bf(v.x); o.y = f2bf(v.y); o.z = f2bf(v.z); o.w = f2bf(v.w);
  ((ushort4*)dst)[i] = o;
}

// ---------- embedding gather -> bf16 [4096][512] ----------
__global__ void gather_xe(const int* __restrict__ x, const float* __restrict__ emb,
                          unsigned short* __restrict__ xe) {
  const int m = blockIdx.x;              // b*256 + t
  const int tok = x[m];
  const float4 v = ((const float4*)(emb + (size_t)tok * 512))[threadIdx.x];
  ushort4 o; o.x = f2bf(v.x); o.y = f2bf(v.y); o.z = f2bf(v.z); o.w = f2bf(v.w);
  ((ushort4*)(xe + (size_t)m * 512))[threadIdx.x] = o;
}

// ---------- h0 = tanh(z @ W_init^T + b_init) ----------
__global__ __launch_bounds__(256) void h0_kernel(const float* __restrict__ z,
                                                 const float* __restrict__ Wi,
                                                 const float* __restrict__ bi,
                                                 float* __restrict__ h0f,
                                                 unsigned short* __restrict__ hg) {
  const int idx = blockIdx.x * 256 + threadIdx.x;  // 0..16383
  const int b = idx & 15, i = idx >> 4;
  const float4* wr = (const float4*)(Wi + (size_t)i * 1024);
  const float4* zr = (const float4*)(z + (size_t)b * 1024);
  float acc = bi[i];
#pragma unroll 4
  for (int k = 0; k < 256; ++k) {
    float4 w = wr[k], zv = zr[k];
    acc += w.x * zv.x + w.y * zv.y + w.z * zv.z + w.w * zv.w;
  }
  float h = tanh_(acc);
  h0f[(size_t)b * 1024 + i] = h;
  hg[(size_t)b * 1024 + i] = f2bf(h);   // parity-0 buffer
}

// ---------- bf16 GEMM, C[M,N] = A[M,K] @ B[N,K]^T + bias ----------
// 128x128 tile, BK=32, 4 waves (each 64x64 = 4x4 frags of 16x16x32 MFMA),
// staging via global_load_lds width-16 (m97 structure).
template <typename OutT>
__global__ __launch_bounds__(256) void gemm_bt(
    const unsigned short* __restrict__ A, const unsigned short* __restrict__ Bm,
    const float* __restrict__ bias, OutT* __restrict__ C,
    int M, int N, int K) {
  __shared__ __align__(16) unsigned short As[128 * 32];
  __shared__ __align__(16) unsigned short Bs[128 * 32];
  const int tid = threadIdx.x;
  const int lane = tid & 63, wave = tid >> 6;
  const int nTM = M >> 7;
  const int bm = blockIdx.x % nTM, bn = blockIdx.x / nTM;
  const long row0 = (long)bm << 7, col0 = (long)bn << 7;
  const int wm = (wave & 1) << 6, wn = (wave >> 1) << 6;

  f32x4 acc[4][4] = {};

  // staging coords: chunk r covers rows r*64 + wave*16 + lane/4, k bytes (lane&3)*16
  const int sr = (wave << 4) + (lane >> 2);
  const int sk = (lane & 3) << 3;
  const unsigned short* Abase = A + ((size_t)(row0 + sr)) * K + sk;
  const unsigned short* Bbase = Bm + ((size_t)(col0 + sr)) * K + sk;
  char* ldsA = (char*)As + wave * 1024;  // wave-uniform LDS base
  char* ldsB = (char*)Bs + wave * 1024;

  for (int k0 = 0; k0 < K; k0 += 32) {
    __syncthreads();                      // previous compute done with LDS
    GLDS(Abase + k0, ldsA);
    GLDS(Abase + (size_t)64 * K + k0, ldsA + 4096);
    GLDS(Bbase + k0, ldsB);
    GLDS(Bbase + (size_t)64 * K + k0, ldsB + 4096);
    __syncthreads();                      // vmcnt(0) drained before barrier
    const int lr = lane & 15, lk = (lane >> 4) << 3;
    bf16x8 af[4], bfr[4];
#pragma unroll
    for (int i = 0; i < 4; ++i) {
      af[i]  = *(const bf16x8*)(As + (wm + i * 16 + lr) * 32 + lk);
      bfr[i] = *(const bf16x8*)(Bs + (wn + i * 16 + lr) * 32 + lk);
    }
#pragma unroll
    for (int i = 0; i < 4; ++i)
#pragma unroll
      for (int j = 0; j < 4; ++j)
        acc[i][j] = __builtin_amdgcn_mfma_f32_16x16x32_bf16(af[i], bfr[j], acc[i][j], 0, 0, 0);
  }

  // epilogue: D row=(lane>>4)*4+q, col=lane&15 (verified gfx950 C/D layout)
  const int lr = lane & 15, lq = (lane >> 4) << 2;
#pragma unroll
  for (int i = 0; i < 4; ++i) {
#pragma unroll
    for (int q = 0; q < 4; ++q) {
      const long r = row0 + wm + i * 16 + lq + q;
      OutT* crow = C + (size_t)r * N;
#pragma unroll
      for (int j = 0; j < 4; ++j) {
        const long cc = col0 + wn + j * 16 + lr;
        float v = acc[i][j][q] + bias[cc];
        if constexpr (sizeof(OutT) == 2) crow[cc] = (OutT)f2bf(v);
        else                             crow[cc] = (OutT)v;
      }
    }
  }
}

// ---------- persistent GRU recurrence ----------
// 128 blocks x 256 thr. Block j owns h cols [8j,8j+8): W_hh rows {i,1024+i,2048+i}
// live in LDS (bf16, XOR-swizzled). Per step: gh = h @ Wslice^T via MFMA
// (A = h from global bf16 parity buffer, K split over 4 waves), GRU elementwise
// in fp32 regs, write next-parity h, device-wide monotonic barrier.
__global__ __launch_bounds__(256) void gru_rec(
    const float* __restrict__ Whh, const float* __restrict__ bhh,
    const unsigned short* __restrict__ gi, const float* __restrict__ h0f,
    unsigned short* __restrict__ hg, unsigned short* __restrict__ hs,
    unsigned int* __restrict__ bar, int nblocks) {
  __shared__ __align__(16) unsigned short Ws[24 * 1024];  // 48 KB
  __shared__ float ghp[4][16][32];                        // 8 KB partials
  const int tid = threadIdx.x, lane = tid & 63, wave = tid >> 6;
  const int j = blockIdx.x;

  // load + convert + swizzle W slice (g 0-7:r, 8-15:z, 16-23:n)
  for (int idx = tid; idx < 24 * 128; idx += 256) {
    const int g = idx >> 7, k8 = (idx & 127) << 3;
    const int grow = ((g >> 3) << 10) + (j << 3) + (g & 7);
    const float* src = Whh + (size_t)grow * 1024 + k8;
    ushort8 o;
#pragma unroll
    for (int e = 0; e < 8; ++e) o[e] = f2bf(src[e]);
    const int db = (g << 11) + ((k8 << 1) ^ ((g & 7) << 4));  // XOR bank-swizzle
    *(ushort8*)((char*)Ws + db) = o;
  }

  const int b = tid >> 3, c = tid & 7;
  const int cg = (j << 3) + c;
  float hreg = 0.f, br = 0.f, bz = 0.f, bn = 0.f;
  if (tid < 128) {
    hreg = h0f[(size_t)b * 1024 + cg];
    br = bhh[cg]; bz = bhh[1024 + cg]; bn = bhh[2048 + cg];
  }
  __syncthreads();

  const int kw = wave << 8;          // 256 k per wave
  const int lr = lane & 15;
  const int g0 = lr;
  const int g1 = (16 + lr > 23) ? 23 : (16 + lr);  // clamp pad rows (cols unread)
  const int x0 = (g0 & 7) << 4, x1 = (g1 & 7) << 4;

  for (int t = 0; t < 256; ++t) {
    float ir = 0.f, iz = 0.f, inn = 0.f;
    if (tid < 128) {
      hs[((size_t)b * 256 + t) * 1024 + cg] = f2bf(hreg);   // state BEFORE step t
      const unsigned short* gr = gi + ((size_t)b * 256 + t) * 3072;
      ir = bf2f(gr[cg]); iz = bf2f(gr[1024 + cg]); inn = bf2f(gr[2048 + cg]);
    }
    const unsigned short* hcur = hg + ((t & 1) << 14);
    f32x4 a0 = {}, a1 = {};
#pragma unroll
    for (int ki = 0; ki < 8; ++ki) {
      const int k = kw + (ki << 5);
      bf16x8 av = *(const bf16x8*)(hcur + lr * 1024 + k + ((lane >> 4) << 3));
      const int kb = (k << 1) + ((lane >> 4) << 4);
      bf16x8 w0 = *(const bf16x8*)((const char*)Ws + (g0 << 11) + (kb ^ x0));
      bf16x8 w1 = *(const bf16x8*)((const char*)Ws + (g1 << 11) + (kb ^ x1));
      a0 = __builtin_amdgcn_mfma_f32_16x16x32_bf16(av, w0, a0, 0, 0, 0);
      a1 = __builtin_amdgcn_mfma_f32_16x16x32_bf16(av, w1, a1, 0, 0, 0);
    }
#pragma unroll
    for (int q = 0; q < 4; ++q) {
      const int rr = ((lane >> 4) << 2) + q;   // = batch row
      ghp[wave][rr][lr] = a0[q];
      ghp[wave][rr][16 + lr] = a1[q];
    }
    __syncthreads();
    if (tid < 128) {
      const float hr = ghp[0][b][c] + ghp[1][b][c] + ghp[2][b][c] + ghp[3][b][c];
      const float hz = ghp[0][b][8 + c] + ghp[1][b][8 + c] + ghp[2][b][8 + c] + ghp[3][b][8 + c];
      const float hn = ghp[0][b][16 + c] + ghp[1][b][16 + c] + ghp[2][b][16 + c] + ghp[3][b][16 + c];
      const float rg = sigm(ir + hr + br);
      const float zg = sigm(iz + hz + bz);
      const float ng = tanh_(inn + rg * (hn + bn));
      hreg = (1.f - zg) * ng + zg * hreg;
      if (t < 255) hg[(((t + 1) & 1) << 14) + b * 1024 + cg] = f2bf(hreg);
    }
    if (t < 255) {
      __syncthreads();                       // all waves' stores drained to L2
      if (tid == 0) {
        __threadfence();                     // agent fence: L2 writeback (cross-XCD)
        __hip_atomic_fetch_add(bar, 1u, __ATOMIC_RELAXED, __HIP_MEMORY_SCOPE_AGENT);
        const unsigned tgt = (unsigned)nblocks * (unsigned)(t + 1);
        long guard = 0;
        while (__hip_atomic_load(bar, __ATOMIC_RELAXED, __HIP_MEMORY_SCOPE_AGENT) < tgt) {
          __builtin_amdgcn_s_sleep(2);
          if (++guard > (1L << 18)) break;   // hang guard (never hit if correct)
        }
        __threadfence();                     // agent acquire: invalidate stale L1/L2
      }
      __syncthreads();
    }
  }
}

// ---------- launch ----------
extern "C" void kernel_launch(void* const* d_in, const int* in_sizes, int n_in,
                              void* d_out, int out_size, void* d_ws, size_t ws_size,
                              hipStream_t stream) {
  const float* z     = (const float*)d_in[0];
  const int*   x     = (const int*)d_in[1];
  const float* emb   = (const float*)d_in[2];
  const float* Winit = (const float*)d_in[3];
  const float* binit = (const float*)d_in[4];
  const float* Wih   = (const float*)d_in[5];
  const float* Whh   = (const float*)d_in[6];
  const float* bih   = (const float*)d_in[7];
  const float* bhh   = (const float*)d_in[8];
  const float* Wout  = (const float*)d_in[9];
  const float* bout  = (const float*)d_in[10];
  float* out = (float*)d_out;

  char* ws = (char*)d_ws;
  size_t off = 0;
  auto alloc = [&](size_t bytes) { void* p = ws + off; off += (bytes + 255) & ~(size_t)255; return p; };
  unsigned int*   bar   = (unsigned int*)alloc(256);
  unsigned short* xe    = (unsigned short*)alloc((size_t)4096 * 512 * 2);
  unsigned short* WihB  = (unsigned short*)alloc((size_t)3072 * 512 * 2);
  unsigned short* WoutB = (unsigned short*)alloc((size_t)32000 * 1024 * 2);
  unsigned short* giB   = (unsigned short*)alloc((size_t)4096 * 3072 * 2);
  unsigned short* hsB   = (unsigned short*)alloc((size_t)4096 * 1024 * 2);
  float*          h0f   = (float*)alloc((size_t)16 * 1024 * 4);
  unsigned short* hg    = (unsigned short*)alloc((size_t)2 * 16 * 1024 * 2);
  (void)ws_size; (void)in_sizes; (void)n_in; (void)out_size;

  hipMemsetAsync(bar, 0, 256, stream);

  // weight conversions
  conv_bf16<<<dim3((3072 * 512 / 4 + 255) / 256), 256, 0, stream>>>(Wih, WihB, 3072 * 512 / 4);
  conv_bf16<<<dim3((32000 * 1024 / 4 + 255) / 256), 256, 0, stream>>>(Wout, WoutB, 32000 * 1024 / 4);

  // embeddings + h0
  gather_xe<<<dim3(4096), 128, 0, stream>>>(x, emb, xe);
  h0_kernel<<<dim3(64), 256, 0, stream>>>(z, Winit, binit, h0f, hg);

  // gi = xe @ W_ih^T + b_ih   [4096, 3072] bf16
  gemm_bt<unsigned short><<<dim3(32 * 24), 256, 0, stream>>>(xe, WihB, bih, giB, 4096, 3072, 512);

  // GRU recurrence -> hs [4096, 1024] bf16
  gru_rec<<<dim3(128), 256, 0, stream>>>(Whh, bhh, giB, h0f, hg, hsB, bar, 128);

  // logits = hs @ W_out^T + b_out  [4096, 32000] fp32
  gemm_bt<float><<<dim3(32 * 250), 256, 0, stream>>>(hsB, WoutB, bout, out, 4096, 32000, 1024);
}